// Round 2
// baseline (1931.111 us; speedup 1.0000x reference)
//
#include <hip/hip_runtime.h>
#include <hip/hip_bf16.h>
#include <math.h>

// AttentionContextEncoder: phases 1-5 fp32 VALU (per-wave, 4-row subgroups),
// MLP1/MLP2 via bf16 MFMA 16x16x32 over 64-row cooperative blocks.
// B=131072, E=64, H=4, D=16, S=5. Out: (B,160) fp32.

#define NROWS 131072
#define M 4
#define WAVES 4
#define ROWS_PER_BLOCK 64

typedef __attribute__((ext_vector_type(8))) short short8;
typedef __attribute__((ext_vector_type(4))) float f32x4;

__device__ __forceinline__ short f2bs(float f) {
  __hip_bfloat16 h = __float2bfloat16(f);
  return *reinterpret_cast<short*>(&h);
}

// ---------------- weight pack kernel: W1,W2 -> bf16 fragment-ordered ----------------
// W1F: 16 ntg x 10 kk x 64 lane x 8 : elem = bf16(W1[k*256+n]), n=16*ntg+(lane&15), k=32*kk+8*(lane>>4)+i
// W2F: 10 ntg x  8 kk x 64 lane x 8 : elem = bf16(W2[k*160+n])
__global__ void pack_weights(const float* __restrict__ W1, const float* __restrict__ W2,
                             short* __restrict__ ws) {
  int idx = blockIdx.x * blockDim.x + threadIdx.x;
  if (idx < 81920) {
    int i = idx & 7, lane = (idx >> 3) & 63;
    int t = idx >> 9;                 // ntg*10 + kk
    int kk = t % 10, ntg = t / 10;
    int n = ntg * 16 + (lane & 15);
    int k = kk * 32 + (lane >> 4) * 8 + i;
    ws[idx] = f2bs(W1[k * 256 + n]);
  } else if (idx < 81920 + 40960) {
    int j = idx - 81920;
    int i = j & 7, lane = (j >> 3) & 63;
    int t = j >> 9;                   // ntg*8 + kk
    int kk = t & 7, ntg = t >> 3;
    int n = ntg * 16 + (lane & 15);
    int k = kk * 32 + (lane >> 4) * 8 + i;
    ws[81920 + j] = f2bs(W2[k * 160 + n]);
  }
}

template<int IN, int HID>
__device__ __forceinline__ void branch_block(
    const float* __restrict__ Wp, const float* __restrict__ bp,
    const float* __restrict__ Wu, const float* __restrict__ bu,
    float* __restrict__ A, float* __restrict__ X, int lane, int in_off, int s)
{
  if (lane < HID) {
    float hh[M];
    #pragma unroll
    for (int m = 0; m < M; ++m) hh[m] = bp[lane];
    #pragma unroll
    for (int i = 0; i < IN; ++i) {
      float w = Wp[i * HID + lane];
      #pragma unroll
      for (int m = 0; m < M; ++m) hh[m] += A[m * 100 + in_off + i] * w;
    }
    #pragma unroll
    for (int m = 0; m < M; ++m) A[400 + m * 64 + lane] = fmaxf(hh[m], 0.0f);
  }
  float xs[M];
  #pragma unroll
  for (int m = 0; m < M; ++m) xs[m] = bu[lane];
  #pragma unroll
  for (int j = 0; j < HID; ++j) {
    float w = Wu[j * 64 + lane];
    #pragma unroll
    for (int m = 0; m < M; ++m) xs[m] += A[400 + m * 64 + j] * w;
  }
  #pragma unroll
  for (int m = 0; m < M; ++m) X[m * 320 + s * 64 + lane] = xs[m];
}

__global__ __launch_bounds__(256, 2) void ace_fused(
    const float* __restrict__ visual, const float* __restrict__ audio,
    const float* __restrict__ pose,   const float* __restrict__ spatial,
    const float* __restrict__ timex,
    const float* __restrict__ Wv_p, const float* __restrict__ bv_p,
    const float* __restrict__ Wa_p, const float* __restrict__ ba_p,
    const float* __restrict__ Wp_p, const float* __restrict__ bp_p,
    const float* __restrict__ Ws_p, const float* __restrict__ bs_p,
    const float* __restrict__ Wt_p, const float* __restrict__ bt_p,
    const float* __restrict__ Wv_u, const float* __restrict__ bv_u,
    const float* __restrict__ Wa_u, const float* __restrict__ ba_u,
    const float* __restrict__ Wp_u, const float* __restrict__ bp_u,
    const float* __restrict__ Ws_u, const float* __restrict__ bs_u,
    const float* __restrict__ Wt_u, const float* __restrict__ bt_u,
    const float* __restrict__ Wq,  const float* __restrict__ bq,
    const float* __restrict__ Wk,  const float* __restrict__ bk,
    const float* __restrict__ Wvv, const float* __restrict__ bvv,
    const float* __restrict__ Wo,  const float* __restrict__ bo,
    const float* __restrict__ gamma, const float* __restrict__ beta,
    const float* __restrict__ b1, const float* __restrict__ b2,
    const short* __restrict__ W1F, const short* __restrict__ W2F,
    float* __restrict__ out)
{
  __shared__ char smem[81920];
  char* flatB   = smem;             // 64 rows * 640 B (bf16 [64][320], XOR-swizzled)
  char* scratch = smem + 40960;     // per-wave 10240 B; later reused as fusedB
  char* fusedB  = scratch;          // 64 rows * 512 B (bf16 [64][256], XOR-swizzled)

  const int tid  = threadIdx.x;
  const int wave = tid >> 6;
  const int lane = tid & 63;
  float* X4 = (float*)(scratch + wave * 10240);          // [4][320] f32: x tokens
  float* B4 = (float*)(scratch + wave * 10240 + 5120);   // [4][320] f32: inputs/hid then o
  const int rowBase = blockIdx.x * ROWS_PER_BLOCK;

  // ================= phase A: branches + QKV + attn + Wo + LN =================
  for (int g = 0; g < 4; ++g) {
    const int rBlk = wave * 16 + g * 4;   // block-row of m=0

    // stage raw inputs
    #pragma unroll
    for (int m = 0; m < M; ++m) {
      const int r = rowBase + rBlk + m;
      if (lane < 14) B4[m * 100 +  0 + lane] = visual [r * 14 + lane];
      if (lane < 17) B4[m * 100 + 14 + lane] = audio  [r * 17 + lane];
      if (lane < 51) B4[m * 100 + 31 + lane] = pose   [r * 51 + lane];
      if (lane <  7) B4[m * 100 + 82 + lane] = spatial[r *  7 + lane];
      if (lane < 10) B4[m * 100 + 89 + lane] = timex  [r * 10 + lane];
    }

    branch_block<14, 32>(Wv_p, bv_p, Wv_u, bv_u, B4, X4, lane,  0, 0);
    branch_block<17, 64>(Wa_p, ba_p, Wa_u, ba_u, B4, X4, lane, 14, 1);
    branch_block<51, 32>(Wp_p, bp_p, Wp_u, bp_u, B4, X4, lane, 31, 2);
    branch_block< 7, 16>(Ws_p, bs_p, Ws_u, bs_u, B4, X4, lane, 82, 3);
    branch_block<10, 16>(Wt_p, bt_p, Wt_u, bt_u, B4, X4, lane, 89, 4);

    // QKV projections (lane = h*16+d)
    float qr[M][5], kr[M][5], vr[M][5];
    {
      const float bqv = bq[lane], bkv = bk[lane], bvv_ = bvv[lane];
      #pragma unroll
      for (int m = 0; m < M; ++m)
        #pragma unroll
        for (int s = 0; s < 5; ++s) { qr[m][s] = bqv; kr[m][s] = bkv; vr[m][s] = bvv_; }
      for (int e = 0; e < 64; ++e) {
        const float wq = Wq[e * 64 + lane];
        const float wk = Wk[e * 64 + lane];
        const float wv = Wvv[e * 64 + lane];
        #pragma unroll
        for (int m = 0; m < M; ++m)
          #pragma unroll
          for (int s = 0; s < 5; ++s) {
            const float xr = X4[m * 320 + s * 64 + e];
            qr[m][s] += xr * wq; kr[m][s] += xr * wk; vr[m][s] += xr * wv;
          }
      }
    }

    // attention in registers (16-lane group reduce over d)
    float orr[M][5];
    #pragma unroll
    for (int m = 0; m < M; ++m) {
      #pragma unroll
      for (int qi = 0; qi < 5; ++qi) {
        float sc[5];
        #pragma unroll
        for (int ki = 0; ki < 5; ++ki) {
          float p = qr[m][qi] * kr[m][ki];
          p += __shfl_xor(p, 1); p += __shfl_xor(p, 2);
          p += __shfl_xor(p, 4); p += __shfl_xor(p, 8);
          sc[ki] = p * 0.25f;
        }
        float mx = fmaxf(fmaxf(fmaxf(sc[0], sc[1]), fmaxf(sc[2], sc[3])), sc[4]);
        float ssum = 0.f;
        #pragma unroll
        for (int ki = 0; ki < 5; ++ki) { sc[ki] = __expf(sc[ki] - mx); ssum += sc[ki]; }
        const float inv = 1.0f / ssum;
        float acc = 0.f;
        #pragma unroll
        for (int ki = 0; ki < 5; ++ki) acc += (sc[ki] * inv) * vr[m][ki];
        orr[m][qi] = acc;
      }
    }

    // stage o (f32, reuse B4), output projection, residual + LN -> flatB bf16
    #pragma unroll
    for (int m = 0; m < M; ++m)
      #pragma unroll
      for (int s = 0; s < 5; ++s) B4[m * 320 + s * 64 + lane] = orr[m][s];

    float att[M][5];
    {
      const float bov = bo[lane];
      #pragma unroll
      for (int m = 0; m < M; ++m)
        #pragma unroll
        for (int s = 0; s < 5; ++s) att[m][s] = bov;
      for (int hd = 0; hd < 64; ++hd) {
        const float w = Wo[hd * 64 + lane];
        #pragma unroll
        for (int m = 0; m < M; ++m)
          #pragma unroll
          for (int s = 0; s < 5; ++s) att[m][s] += B4[m * 320 + s * 64 + hd] * w;
      }
    }
    {
      const float ga = gamma[lane], be = beta[lane];
      #pragma unroll
      for (int m = 0; m < M; ++m) {
        const int row = rBlk + m;
        char* rowp = flatB + row * 640;
        const int swz = (row & 7) << 4;
        #pragma unroll
        for (int s = 0; s < 5; ++s) {
          const float hv = X4[m * 320 + s * 64 + lane] + att[m][s];
          float s1 = hv, s2 = hv * hv;
          #pragma unroll
          for (int off = 32; off >= 1; off >>= 1) {
            s1 += __shfl_xor(s1, off);
            s2 += __shfl_xor(s2, off);
          }
          const float mean = s1 * 0.015625f;
          const float var  = s2 * 0.015625f - mean * mean;
          const float hn = (hv - mean) * rsqrtf(var + 1e-3f) * ga + be;
          *(short*)(rowp + (((s * 64 + lane) * 2) ^ swz)) = f2bs(hn);
        }
      }
    }
  }
  __syncthreads();

  // ================= phase B: MLP1 via MFMA =================
  // fused[64][256] = relu(flat[64][320] @ W1 + b1); wave w owns cols 64w..64w+63
  const int r15 = lane & 15, g4 = lane >> 4;
  {
    f32x4 acc[4][4] = {};
    for (int kk = 0; kk < 10; ++kk) {
      short8 a[4], b[4];
      #pragma unroll
      for (int mt = 0; mt < 4; ++mt) {
        const int row = mt * 16 + r15;
        a[mt] = *(const short8*)(flatB + row * 640 + ((kk * 64 + g4 * 16) ^ ((row & 7) << 4)));
      }
      #pragma unroll
      for (int nt = 0; nt < 4; ++nt) {
        const int ntg = wave * 4 + nt;
        b[nt] = *(const short8*)(W1F + ((ntg * 10 + kk) * 64 + lane) * 8);
      }
      #pragma unroll
      for (int mt = 0; mt < 4; ++mt)
        #pragma unroll
        for (int nt = 0; nt < 4; ++nt)
          acc[mt][nt] = __builtin_amdgcn_mfma_f32_16x16x32_bf16(a[mt], b[nt], acc[mt][nt], 0, 0, 0);
    }
    __syncthreads();   // phase-A scratch (X4/B4) dead everywhere; fusedB may now be written
    #pragma unroll
    for (int nt = 0; nt < 4; ++nt) {
      const int c = wave * 64 + nt * 16 + r15;
      const float bias = b1[c];
      #pragma unroll
      for (int mt = 0; mt < 4; ++mt)
        #pragma unroll
        for (int j = 0; j < 4; ++j) {
          const int row = mt * 16 + g4 * 4 + j;
          const float v = fmaxf(acc[mt][nt][j] + bias, 0.0f);
          *(short*)(fusedB + row * 512 + ((c * 2) ^ ((row & 7) << 4))) = f2bs(v);
        }
    }
  }
  __syncthreads();

  // ================= phase C: MLP2 via MFMA =================
  // out[64][160] = relu(fused[64][256] @ W2 + b2); wave w owns N-tiles {w, w+4, w+8}
  {
    const int nOwn = (wave < 2) ? 3 : 2;
    f32x4 acc[3][4] = {};
    for (int kk = 0; kk < 8; ++kk) {
      short8 a[4];
      #pragma unroll
      for (int mt = 0; mt < 4; ++mt) {
        const int row = mt * 16 + r15;
        a[mt] = *(const short8*)(fusedB + row * 512 + ((kk * 64 + g4 * 16) ^ ((row & 7) << 4)));
      }
      #pragma unroll
      for (int t = 0; t < 3; ++t) {
        if (t < nOwn) {
          const int ntg = wave + t * 4;
          const short8 b = *(const short8*)(W2F + ((ntg * 8 + kk) * 64 + lane) * 8);
          #pragma unroll
          for (int mt = 0; mt < 4; ++mt)
            acc[t][mt] = __builtin_amdgcn_mfma_f32_16x16x32_bf16(a[mt], b, acc[t][mt], 0, 0, 0);
        }
      }
    }
    #pragma unroll
    for (int t = 0; t < 3; ++t) {
      if (t < nOwn) {
        const int c = (wave + t * 4) * 16 + r15;
        const float bias = b2[c];
        #pragma unroll
        for (int mt = 0; mt < 4; ++mt)
          #pragma unroll
          for (int j = 0; j < 4; ++j) {
            const int row = mt * 16 + g4 * 4 + j;
            out[(size_t)(rowBase + row) * 160 + c] = fmaxf(acc[t][mt][j] + bias, 0.0f);
          }
      }
    }
  }
}

extern "C" void kernel_launch(void* const* d_in, const int* in_sizes, int n_in,
                              void* d_out, int out_size, void* d_ws, size_t ws_size,
                              hipStream_t stream) {
  const float* visual  = (const float*)d_in[0];
  const float* audio   = (const float*)d_in[1];
  const float* pose    = (const float*)d_in[2];
  const float* spatial = (const float*)d_in[3];
  const float* timex   = (const float*)d_in[4];
  const float* Wv_p = (const float*)d_in[5];  const float* bv_p = (const float*)d_in[6];
  const float* Wa_p = (const float*)d_in[7];  const float* ba_p = (const float*)d_in[8];
  const float* Wp_p = (const float*)d_in[9];  const float* bp_p = (const float*)d_in[10];
  const float* Ws_p = (const float*)d_in[11]; const float* bs_p = (const float*)d_in[12];
  const float* Wt_p = (const float*)d_in[13]; const float* bt_p = (const float*)d_in[14];
  const float* Wv_u = (const float*)d_in[15]; const float* bv_u = (const float*)d_in[16];
  const float* Wa_u = (const float*)d_in[17]; const float* ba_u = (const float*)d_in[18];
  const float* Wp_u = (const float*)d_in[19]; const float* bp_u = (const float*)d_in[20];
  const float* Ws_u = (const float*)d_in[21]; const float* bs_u = (const float*)d_in[22];
  const float* Wt_u = (const float*)d_in[23]; const float* bt_u = (const float*)d_in[24];
  const float* Wq  = (const float*)d_in[25];  const float* bq  = (const float*)d_in[26];
  const float* Wk  = (const float*)d_in[27];  const float* bk  = (const float*)d_in[28];
  const float* Wvv = (const float*)d_in[29];  const float* bvv = (const float*)d_in[30];
  const float* Wo  = (const float*)d_in[31];  const float* bo  = (const float*)d_in[32];
  const float* gamma = (const float*)d_in[33]; const float* beta = (const float*)d_in[34];
  const float* W1 = (const float*)d_in[35];   const float* b1 = (const float*)d_in[36];
  const float* W2 = (const float*)d_in[37];   const float* b2 = (const float*)d_in[38];
  float* out = (float*)d_out;

  short* W1F = (short*)d_ws;            // 81920 bf16
  short* W2F = W1F + 81920;             // 40960 bf16  (total 245760 B of d_ws)

  hipLaunchKernelGGL(pack_weights, dim3(480), dim3(256), 0, stream, W1, W2, W1F);

  const int grid = NROWS / ROWS_PER_BLOCK;   // 2048
  hipLaunchKernelGGL(ace_fused, dim3(grid), dim3(256), 0, stream,
                     visual, audio, pose, spatial, timex,
                     Wv_p, bv_p, Wa_p, ba_p, Wp_p, bp_p, Ws_p, bs_p, Wt_p, bt_p,
                     Wv_u, bv_u, Wa_u, ba_u, Wp_u, bp_u, Ws_u, bs_u, Wt_u, bt_u,
                     Wq, bq, Wk, bk, Wvv, bvv, Wo, bo, gamma, beta,
                     b1, b2, W1F, W2F, out);
}

// Round 3
// 784.967 us; speedup vs baseline: 2.4601x; 2.4601x over previous
//
#include <hip/hip_runtime.h>
#include <hip/hip_bf16.h>
#include <math.h>

// Two-kernel AttentionContextEncoder:
//  A) per-wave fp32: branches + QKV + attn + Wo + residual/LN -> flat bf16 (B,320) in d_ws (XOR-swizzled)
//  B) MFMA MLP: relu(relu(flat@W1+b1)@W2+b2) -> out (B,160) fp32, coalesced epilogue
// B=131072, E=64, H=4, D=16, S=5.

#define NROWS 131072
#define M 4
#define WAVES 4
#define BROWS 128

typedef __attribute__((ext_vector_type(8))) short short8;
typedef __attribute__((ext_vector_type(4))) float f32x4;

__device__ __forceinline__ short f2bs(float f) {
  __hip_bfloat16 h = __float2bfloat16(f);
  return *reinterpret_cast<short*>(&h);
}

#define GLOAD_LDS16(g, l) __builtin_amdgcn_global_load_lds( \
    (const __attribute__((address_space(1))) void*)(g),     \
    (__attribute__((address_space(3))) void*)(l), 16, 0, 0)

// ---------------- weight pack: W1,W2 -> bf16 fragment-ordered ----------------
__global__ void pack_weights(const float* __restrict__ W1, const float* __restrict__ W2,
                             short* __restrict__ ws) {
  int idx = blockIdx.x * blockDim.x + threadIdx.x;
  if (idx < 81920) {
    int i = idx & 7, lane = (idx >> 3) & 63;
    int t = idx >> 9;                 // ntg*10 + kk
    int kk = t % 10, ntg = t / 10;
    int n = ntg * 16 + (lane & 15);
    int k = kk * 32 + (lane >> 4) * 8 + i;
    ws[idx] = f2bs(W1[k * 256 + n]);
  } else if (idx < 81920 + 40960) {
    int j = idx - 81920;
    int i = j & 7, lane = (j >> 3) & 63;
    int t = j >> 9;                   // ntg*8 + kk
    int kk = t & 7, ntg = t >> 3;
    int n = ntg * 16 + (lane & 15);
    int k = kk * 32 + (lane >> 4) * 8 + i;
    ws[81920 + j] = f2bs(W2[k * 160 + n]);
  }
}

template<int IN, int HID>
__device__ __forceinline__ void branch_block(
    const float* __restrict__ Wp, const float* __restrict__ bp,
    const float* __restrict__ Wu, const float* __restrict__ bu,
    float* __restrict__ A, float* __restrict__ X, int lane, int in_off, int s)
{
  if (lane < HID) {
    float hh[M];
    #pragma unroll
    for (int m = 0; m < M; ++m) hh[m] = bp[lane];
    #pragma unroll
    for (int i = 0; i < IN; ++i) {
      float w = Wp[i * HID + lane];
      #pragma unroll
      for (int m = 0; m < M; ++m) hh[m] += A[m * 100 + in_off + i] * w;
    }
    #pragma unroll
    for (int m = 0; m < M; ++m) A[400 + m * 64 + lane] = fmaxf(hh[m], 0.0f);
  }
  float xs[M];
  #pragma unroll
  for (int m = 0; m < M; ++m) xs[m] = bu[lane];
  #pragma unroll
  for (int j = 0; j < HID; ++j) {
    float w = Wu[j * 64 + lane];
    #pragma unroll
    for (int m = 0; m < M; ++m) xs[m] += A[400 + m * 64 + j] * w;
  }
  #pragma unroll
  for (int m = 0; m < M; ++m) X[m * 320 + s * 64 + lane] = xs[m];
}

// ================= kernel A: branches + QKV + attn + Wo + LN =================
__global__ __launch_bounds__(256, 2) void ace_front(
    const float* __restrict__ visual, const float* __restrict__ audio,
    const float* __restrict__ pose,   const float* __restrict__ spatial,
    const float* __restrict__ timex,
    const float* __restrict__ Wv_p, const float* __restrict__ bv_p,
    const float* __restrict__ Wa_p, const float* __restrict__ ba_p,
    const float* __restrict__ Wp_p, const float* __restrict__ bp_p,
    const float* __restrict__ Ws_p, const float* __restrict__ bs_p,
    const float* __restrict__ Wt_p, const float* __restrict__ bt_p,
    const float* __restrict__ Wv_u, const float* __restrict__ bv_u,
    const float* __restrict__ Wa_u, const float* __restrict__ ba_u,
    const float* __restrict__ Wp_u, const float* __restrict__ bp_u,
    const float* __restrict__ Ws_u, const float* __restrict__ bs_u,
    const float* __restrict__ Wt_u, const float* __restrict__ bt_u,
    const float* __restrict__ Wq,  const float* __restrict__ bq,
    const float* __restrict__ Wk,  const float* __restrict__ bk,
    const float* __restrict__ Wvv, const float* __restrict__ bvv,
    const float* __restrict__ Wo,  const float* __restrict__ bo,
    const float* __restrict__ gamma, const float* __restrict__ beta,
    char* __restrict__ xg)   // bf16 [NROWS][320], byte (col*2)^((row&7)<<4)
{
  __shared__ float lds[WAVES][2560];
  const int tid  = threadIdx.x;
  const int wave = tid >> 6;
  const int lane = tid & 63;
  float* X = lds[wave];
  float* A = X + 1280;
  const int rowBase = (blockIdx.x * WAVES + wave) * M;

  #pragma unroll
  for (int m = 0; m < M; ++m) {
    const int r = rowBase + m;
    if (lane < 14) A[m * 100 +  0 + lane] = visual [r * 14 + lane];
    if (lane < 17) A[m * 100 + 14 + lane] = audio  [r * 17 + lane];
    if (lane < 51) A[m * 100 + 31 + lane] = pose   [r * 51 + lane];
    if (lane <  7) A[m * 100 + 82 + lane] = spatial[r *  7 + lane];
    if (lane < 10) A[m * 100 + 89 + lane] = timex  [r * 10 + lane];
  }

  branch_block<14, 32>(Wv_p, bv_p, Wv_u, bv_u, A, X, lane,  0, 0);
  branch_block<17, 64>(Wa_p, ba_p, Wa_u, ba_u, A, X, lane, 14, 1);
  branch_block<51, 32>(Wp_p, bp_p, Wp_u, bp_u, A, X, lane, 31, 2);
  branch_block< 7, 16>(Ws_p, bs_p, Ws_u, bs_u, A, X, lane, 82, 3);
  branch_block<10, 16>(Wt_p, bt_p, Wt_u, bt_u, A, X, lane, 89, 4);

  float qr[M][5], kr[M][5], vr[M][5];
  {
    const float bqv = bq[lane], bkv = bk[lane], bvv_ = bvv[lane];
    #pragma unroll
    for (int m = 0; m < M; ++m)
      #pragma unroll
      for (int s = 0; s < 5; ++s) { qr[m][s] = bqv; kr[m][s] = bkv; vr[m][s] = bvv_; }
    for (int e = 0; e < 64; ++e) {
      const float wq = Wq[e * 64 + lane];
      const float wk = Wk[e * 64 + lane];
      const float wv = Wvv[e * 64 + lane];
      #pragma unroll
      for (int m = 0; m < M; ++m)
        #pragma unroll
        for (int s = 0; s < 5; ++s) {
          const float xr = X[m * 320 + s * 64 + e];
          qr[m][s] += xr * wq; kr[m][s] += xr * wk; vr[m][s] += xr * wv;
        }
    }
  }

  float orr[M][5];
  #pragma unroll
  for (int m = 0; m < M; ++m) {
    #pragma unroll
    for (int qi = 0; qi < 5; ++qi) {
      float sc[5];
      #pragma unroll
      for (int ki = 0; ki < 5; ++ki) {
        float p = qr[m][qi] * kr[m][ki];
        p += __shfl_xor(p, 1); p += __shfl_xor(p, 2);
        p += __shfl_xor(p, 4); p += __shfl_xor(p, 8);
        sc[ki] = p * 0.25f;
      }
      float mx = fmaxf(fmaxf(fmaxf(sc[0], sc[1]), fmaxf(sc[2], sc[3])), sc[4]);
      float ssum = 0.f;
      #pragma unroll
      for (int ki = 0; ki < 5; ++ki) { sc[ki] = __expf(sc[ki] - mx); ssum += sc[ki]; }
      const float inv = 1.0f / ssum;
      float acc = 0.f;
      #pragma unroll
      for (int ki = 0; ki < 5; ++ki) acc += (sc[ki] * inv) * vr[m][ki];
      orr[m][qi] = acc;
    }
  }

  #pragma unroll
  for (int m = 0; m < M; ++m)
    #pragma unroll
    for (int s = 0; s < 5; ++s) A[m * 320 + s * 64 + lane] = orr[m][s];

  float att[M][5];
  {
    const float bov = bo[lane];
    #pragma unroll
    for (int m = 0; m < M; ++m)
      #pragma unroll
      for (int s = 0; s < 5; ++s) att[m][s] = bov;
    for (int hd = 0; hd < 64; ++hd) {
      const float w = Wo[hd * 64 + lane];
      #pragma unroll
      for (int m = 0; m < M; ++m)
        #pragma unroll
        for (int s = 0; s < 5; ++s) att[m][s] += A[m * 320 + s * 64 + hd] * w;
    }
  }
  {
    const float ga = gamma[lane], be = beta[lane];
    #pragma unroll
    for (int m = 0; m < M; ++m) {
      const int r = rowBase + m;
      char* rowp = xg + (size_t)r * 640;
      const int swz = (r & 7) << 4;
      #pragma unroll
      for (int s = 0; s < 5; ++s) {
        const float hv = X[m * 320 + s * 64 + lane] + att[m][s];
        float s1 = hv, s2 = hv * hv;
        #pragma unroll
        for (int off = 32; off >= 1; off >>= 1) {
          s1 += __shfl_xor(s1, off);
          s2 += __shfl_xor(s2, off);
        }
        const float mean = s1 * 0.015625f;
        const float var  = s2 * 0.015625f - mean * mean;
        const float hn = (hv - mean) * rsqrtf(var + 1e-3f) * ga + be;
        *(short*)(rowp + (((s * 64 + lane) * 2) ^ swz)) = f2bs(hn);
      }
    }
  }
}

// ================= kernel B: MLP via MFMA, 128 rows/block, 8 waves =================
__global__ __launch_bounds__(512) void ace_mlp(
    const char* __restrict__ xg,
    const short* __restrict__ W1F, const short* __restrict__ W2F,
    const float* __restrict__ b1, const float* __restrict__ b2,
    float* __restrict__ out)
{
  __shared__ char smem[81920];   // X tile [128][640B] -> fused [128][512B] -> C [128][160]f32
  const int tid  = threadIdx.x;
  const int wave = tid >> 6;     // 0..7
  const int lane = tid & 63;
  const int r15 = lane & 15, g4 = lane >> 4;
  const size_t rowBase = (size_t)blockIdx.x * BROWS;

  // ---- stage X tile: 81920 B linear (swizzle pre-baked in global) ----
  {
    const char* src = xg + rowBase * 640;
    #pragma unroll
    for (int i = 0; i < 10; ++i) {
      const int off = i * 8192 + wave * 1024;
      GLOAD_LDS16(src + off + lane * 16, smem + off);
    }
  }
  __syncthreads();

  // ---- GEMM1: fused[128][256] = relu(X @ W1 + b1); wave owns cols wave*32..+32 ----
  f32x4 acc1[8][2] = {};
  for (int kk = 0; kk < 10; ++kk) {
    short8 b[2];
    #pragma unroll
    for (int nt = 0; nt < 2; ++nt)
      b[nt] = *(const short8*)(W1F + (((wave * 2 + nt) * 10 + kk) * 64 + lane) * 8);
    #pragma unroll
    for (int mt = 0; mt < 8; ++mt) {
      const int row = mt * 16 + r15;
      short8 a = *(const short8*)(smem + row * 640 + ((kk * 64 + g4 * 16) ^ ((row & 7) << 4)));
      #pragma unroll
      for (int nt = 0; nt < 2; ++nt)
        acc1[mt][nt] = __builtin_amdgcn_mfma_f32_16x16x32_bf16(a, b[nt], acc1[mt][nt], 0, 0, 0);
    }
  }
  __syncthreads();   // all X reads done; reuse smem for fused

  #pragma unroll
  for (int nt = 0; nt < 2; ++nt) {
    const int c = wave * 32 + nt * 16 + r15;
    const float bias = b1[c];
    #pragma unroll
    for (int mt = 0; mt < 8; ++mt)
      #pragma unroll
      for (int j = 0; j < 4; ++j) {
        const int row = mt * 16 + g4 * 4 + j;
        *(short*)(smem + row * 512 + ((c * 2) ^ ((row & 7) << 4))) =
            f2bs(fmaxf(acc1[mt][nt][j] + bias, 0.0f));
      }
  }
  __syncthreads();

  // ---- GEMM2: C[128][160] = relu(fused @ W2 + b2); wave owns n-tile wave (+8 if wave<2) ----
  const int nOwn2 = (wave < 2) ? 2 : 1;
  f32x4 acc2[2][8] = {};
  for (int kk = 0; kk < 8; ++kk) {
    short8 b0 = *(const short8*)(W2F + ((wave * 8 + kk) * 64 + lane) * 8);
    short8 b1f = (wave < 2)
        ? *(const short8*)(W2F + (((8 + wave) * 8 + kk) * 64 + lane) * 8) : short8{};
    #pragma unroll
    for (int mt = 0; mt < 8; ++mt) {
      const int row = mt * 16 + r15;
      short8 a = *(const short8*)(smem + row * 512 + ((kk * 64 + g4 * 16) ^ ((row & 7) << 4)));
      acc2[0][mt] = __builtin_amdgcn_mfma_f32_16x16x32_bf16(a, b0, acc2[0][mt], 0, 0, 0);
      if (wave < 2)
        acc2[1][mt] = __builtin_amdgcn_mfma_f32_16x16x32_bf16(a, b1f, acc2[1][mt], 0, 0, 0);
    }
  }
  __syncthreads();   // fused reads done; reuse smem for C f32

  #pragma unroll
  for (int t = 0; t < 2; ++t) {
    if (t < nOwn2) {
      const int c = ((t == 0) ? wave : 8 + wave) * 16 + r15;
      const float bias = b2[c];
      #pragma unroll
      for (int mt = 0; mt < 8; ++mt)
        #pragma unroll
        for (int j = 0; j < 4; ++j) {
          const int row = mt * 16 + g4 * 4 + j;
          *(float*)(smem + (row * 160 + c) * 4) = fmaxf(acc2[t][mt][j] + bias, 0.0f);
        }
    }
  }
  __syncthreads();

  // ---- coalesced epilogue: 81920 B -> out ----
  {
    f32x4* dst = (f32x4*)(out + rowBase * 160);
    const f32x4* s4 = (const f32x4*)smem;
    #pragma unroll
    for (int i = 0; i < 10; ++i)
      dst[i * 512 + tid] = s4[i * 512 + tid];
  }
}

extern "C" void kernel_launch(void* const* d_in, const int* in_sizes, int n_in,
                              void* d_out, int out_size, void* d_ws, size_t ws_size,
                              hipStream_t stream) {
  const float* visual  = (const float*)d_in[0];
  const float* audio   = (const float*)d_in[1];
  const float* pose    = (const float*)d_in[2];
  const float* spatial = (const float*)d_in[3];
  const float* timex   = (const float*)d_in[4];
  const float* Wv_p = (const float*)d_in[5];  const float* bv_p = (const float*)d_in[6];
  const float* Wa_p = (const float*)d_in[7];  const float* ba_p = (const float*)d_in[8];
  const float* Wp_p = (const float*)d_in[9];  const float* bp_p = (const float*)d_in[10];
  const float* Ws_p = (const float*)d_in[11]; const float* bs_p = (const float*)d_in[12];
  const float* Wt_p = (const float*)d_in[13]; const float* bt_p = (const float*)d_in[14];
  const float* Wv_u = (const float*)d_in[15]; const float* bv_u = (const float*)d_in[16];
  const float* Wa_u = (const float*)d_in[17]; const float* ba_u = (const float*)d_in[18];
  const float* Wp_u = (const float*)d_in[19]; const float* bp_u = (const float*)d_in[20];
  const float* Ws_u = (const float*)d_in[21]; const float* bs_u = (const float*)d_in[22];
  const float* Wt_u = (const float*)d_in[23]; const float* bt_u = (const float*)d_in[24];
  const float* Wq  = (const float*)d_in[25];  const float* bq  = (const float*)d_in[26];
  const float* Wk  = (const float*)d_in[27];  const float* bk  = (const float*)d_in[28];
  const float* Wvv = (const float*)d_in[29];  const float* bvv = (const float*)d_in[30];
  const float* Wo  = (const float*)d_in[31];  const float* bo  = (const float*)d_in[32];
  const float* gamma = (const float*)d_in[33]; const float* beta = (const float*)d_in[34];
  const float* W1 = (const float*)d_in[35];   const float* b1 = (const float*)d_in[36];
  const float* W2 = (const float*)d_in[37];   const float* b2 = (const float*)d_in[38];
  float* out = (float*)d_out;

  short* W1F = (short*)d_ws;                       // 81920 bf16
  short* W2F = W1F + 81920;                        // 40960 bf16
  char*  xg  = (char*)d_ws + 262144;               // 131072*640 B = 80 MiB

  hipLaunchKernelGGL(pack_weights, dim3(480), dim3(256), 0, stream, W1, W2, W1F);

  hipLaunchKernelGGL(ace_front, dim3(NROWS / (WAVES * M)), dim3(256), 0, stream,
                     visual, audio, pose, spatial, timex,
                     Wv_p, bv_p, Wa_p, ba_p, Wp_p, bp_p, Ws_p, bs_p, Wt_p, bt_p,
                     Wv_u, bv_u, Wa_u, ba_u, Wp_u, bp_u, Ws_u, bs_u, Wt_u, bt_u,
                     Wq, bq, Wk, bk, Wvv, bvv, Wo, bo, gamma, beta, xg);

  hipLaunchKernelGGL(ace_mlp, dim3(NROWS / BROWS), dim3(512), 0, stream,
                     xg, W1F, W2F, b1, b2, out);
}

// Round 4
// 595.993 us; speedup vs baseline: 3.2402x; 1.3171x over previous
//
#include <hip/hip_runtime.h>
#include <hip/hip_bf16.h>
#include <math.h>

// AttentionContextEncoder, round 4:
//  pack_weights: W1,W2 -> bf16 MFMA B-frag tables (proven)
//  pack_front:   fused/transposed fp32 weight tables for the VALU front
//  ace_front:    branches + fused-QKV + attn + Wo + LN, fp32 pk-fma, -> flat bf16 xg
//  ace_mlp:      MFMA MLP (proven)
// B=131072, E=64, H=4, D=16, S=5. Out: (B,160) fp32.

#define NROWS 131072
#define M 4
#define WAVES 4
#define BROWS 128

typedef __attribute__((ext_vector_type(8))) short short8;
typedef __attribute__((ext_vector_type(4))) float f32x4;
typedef __attribute__((ext_vector_type(2))) float f32x2;

__device__ __forceinline__ short f2bs(float f) {
  __hip_bfloat16 h = __float2bfloat16(f);
  return *reinterpret_cast<short*>(&h);
}

__device__ __forceinline__ void pkfma(f32x2& acc, f32x2 a, f32x2 b) {
#if __has_builtin(__builtin_elementwise_fma)
  acc = __builtin_elementwise_fma(a, b, acc);
#else
  acc.x = fmaf(a.x, b.x, acc.x);
  acc.y = fmaf(a.y, b.y, acc.y);
#endif
}

#define GLOAD_LDS16(g, l) __builtin_amdgcn_global_load_lds( \
    (const __attribute__((address_space(1))) void*)(g),     \
    (__attribute__((address_space(3))) void*)(l), 16, 0, 0)

// ---- f32 pool layout (element offsets; pool is 16B-aligned) ----
#define OFF_WPT 0
#define OFF_WUT 3776
#define OFF_WFT 14016
#define OFF_WOT 44736
#define OFF_BQ  48832
#define POOL_N  49792

// ---------------- pack 1: W1,W2 -> bf16 fragment-ordered (proven) ----------------
__global__ void pack_weights(const float* __restrict__ W1, const float* __restrict__ W2,
                             short* __restrict__ ws) {
  int idx = blockIdx.x * blockDim.x + threadIdx.x;
  if (idx < 81920) {
    int i = idx & 7, lane = (idx >> 3) & 63;
    int t = idx >> 9;                 // ntg*10 + kk
    int kk = t % 10, ntg = t / 10;
    int n = ntg * 16 + (lane & 15);
    int k = kk * 32 + (lane >> 4) * 8 + i;
    ws[idx] = f2bs(W1[k * 256 + n]);
  } else if (idx < 81920 + 40960) {
    int j = idx - 81920;
    int i = j & 7, lane = (j >> 3) & 63;
    int t = j >> 9;                   // ntg*8 + kk
    int kk = t & 7, ntg = t >> 3;
    int n = ntg * 16 + (lane & 15);
    int k = kk * 32 + (lane >> 4) * 8 + i;
    ws[81920 + j] = f2bs(W2[k * 160 + n]);
  }
}

// ---------------- pack 2: fused/transposed fp32 front tables ----------------
// WPT[s]: [ICNT][hid][4]   = Wp_s[i][j], zero-padded over i
// WUT[s]: [JCNT][64][4]    = Wu_s[j][e]
// WFT[s]: [3][JCNT][64][4] = sum_e Wu_s[j][e] * W{q,k,v}[e][hd]
// WOT:    [16][64][4]      = Wo[hd][e]
// BQ:     [5][3][64]       = b_{q,k,v}[hd] + sum_e bu_s[e]*W[e][hd]
__global__ void pack_front(
    const float* __restrict__ Wv_p, const float* __restrict__ Wa_p,
    const float* __restrict__ Wp_p, const float* __restrict__ Ws_p,
    const float* __restrict__ Wt_p,
    const float* __restrict__ Wv_u, const float* __restrict__ Wa_u,
    const float* __restrict__ Wp_u, const float* __restrict__ Ws_u,
    const float* __restrict__ Wt_u,
    const float* __restrict__ bv_u, const float* __restrict__ ba_u,
    const float* __restrict__ bp_u, const float* __restrict__ bs_u,
    const float* __restrict__ bt_u,
    const float* __restrict__ Wq, const float* __restrict__ Wk,
    const float* __restrict__ Wvv,
    const float* __restrict__ bq, const float* __restrict__ bk,
    const float* __restrict__ bvv,
    const float* __restrict__ Wo,
    float* __restrict__ pool)
{
  int idx = blockIdx.x * blockDim.x + threadIdx.x;
  if (idx >= POOL_N) return;
  const float* WP[5]  = {Wv_p, Wa_p, Wp_p, Ws_p, Wt_p};
  const float* WU[5]  = {Wv_u, Wa_u, Wp_u, Ws_u, Wt_u};
  const float* BUU[5] = {bv_u, ba_u, bp_u, bs_u, bt_u};
  const float* WT[3]  = {Wq, Wk, Wvv};
  const float* BT[3]  = {bq, bk, bvv};
  const int INs[5]  = {14, 17, 51, 7, 10};
  const int HIDs[5] = {32, 64, 32, 16, 16};
  const int ICNT[5] = {4, 5, 13, 2, 3};
  const int JCNT[5] = {8, 16, 8, 4, 4};
  float val = 0.f;
  if (idx < OFF_WUT) {
    int r = idx, s = 0;
    while (r >= ICNT[s] * HIDs[s] * 4) { r -= ICNT[s] * HIDs[s] * 4; ++s; }
    int ic = r / (HIDs[s] * 4);
    int j  = (r / 4) % HIDs[s];
    int c  = r & 3;
    int i  = ic * 4 + c;
    val = (i < INs[s]) ? WP[s][i * HIDs[s] + j] : 0.f;
  } else if (idx < OFF_WFT) {
    int r = idx - OFF_WUT, s = 0;
    while (r >= JCNT[s] * 256) { r -= JCNT[s] * 256; ++s; }
    int jc = r / 256;
    int e  = (r / 4) & 63;
    int c  = r & 3;
    val = WU[s][(jc * 4 + c) * 64 + e];
  } else if (idx < OFF_WOT) {
    int r = idx - OFF_WFT, s = 0;
    while (r >= 3 * JCNT[s] * 256) { r -= 3 * JCNT[s] * 256; ++s; }
    int t  = r / (JCNT[s] * 256);
    int r2 = r % (JCNT[s] * 256);
    int jc = r2 / 256;
    int hd = (r2 / 4) & 63;
    int c  = r2 & 3;
    int j  = jc * 4 + c;
    float acc = 0.f;
    for (int e = 0; e < 64; ++e) acc += WU[s][j * 64 + e] * WT[t][e * 64 + hd];
    val = acc;
  } else if (idx < OFF_BQ) {
    int r = idx - OFF_WOT;
    int hdc = r / 256;
    int e   = (r / 4) & 63;
    int c   = r & 3;
    val = Wo[(hdc * 4 + c) * 64 + e];
  } else {
    int r = idx - OFF_BQ;
    int s = r / 192;
    int t = (r / 64) % 3;
    int hd = r & 63;
    float acc = BT[t][hd];
    for (int e = 0; e < 64; ++e) acc += BUU[s][e] * WT[t][e * 64 + hd];
    val = acc;
  }
  pool[idx] = val;
}

// ================= kernel A: front, fp32 pk-fma =================
__global__ __launch_bounds__(256, 2) void ace_front(
    const float* __restrict__ visual, const float* __restrict__ audio,
    const float* __restrict__ pose,   const float* __restrict__ spatial,
    const float* __restrict__ timex,
    const float* __restrict__ bv_p, const float* __restrict__ ba_p,
    const float* __restrict__ bp_p, const float* __restrict__ bs_p,
    const float* __restrict__ bt_p,
    const float* __restrict__ bv_u, const float* __restrict__ ba_u,
    const float* __restrict__ bp_u, const float* __restrict__ bs_u,
    const float* __restrict__ bt_u,
    const float* __restrict__ bo, const float* __restrict__ gamma,
    const float* __restrict__ beta,
    const float* __restrict__ pool,
    char* __restrict__ xg)   // bf16 [NROWS][320], byte (col*2)^((row&7)<<4)
{
  // per-wave LDS: region A [0..1280): in[m][112] @0 (448) + hid[m][160] @448 (640);
  //               o rows overlay A [0..1280) after QKV; X [1280..2560): x[m][s][64]
  __shared__ float lds[WAVES][2560];
  const int tid  = threadIdx.x;
  const int wave = tid >> 6;
  const int lane = tid & 63;
  float* A = lds[wave];
  float* X = A + 1280;
  const int rowBase = (blockIdx.x * WAVES + wave) * M;

  const int HIDs[5] = {32, 64, 32, 16, 16};
  const int ICNT[5] = {4, 5, 13, 2, 3};
  const int JCNT[5] = {8, 16, 8, 4, 4};
  const int IOFF[5] = {0, 16, 36, 92, 100};
  const int HOFF[5] = {0, 32, 96, 128, 144};
  const int WPT_OFF[5] = {0, 512, 1792, 3456, 3584};
  const int WUT_OFF[5] = {0, 2048, 6144, 8192, 9216};
  const int WFT_OFF[5] = {0, 6144, 18432, 24576, 27648};
  const float* BP[5] = {bv_p, ba_p, bp_p, bs_p, bt_p};
  const float* BU[5] = {bv_u, ba_u, bp_u, bs_u, bt_u};

  // ---- zero padded input region, then stage raw inputs ----
  #pragma unroll
  for (int k2 = 0; k2 < 7; ++k2) A[k2 * 64 + lane] = 0.f;
  #pragma unroll
  for (int m = 0; m < M; ++m) {
    const int r = rowBase + m;
    if (lane < 14) A[m * 112 +   0 + lane] = visual [r * 14 + lane];
    if (lane < 17) A[m * 112 +  16 + lane] = audio  [r * 17 + lane];
    if (lane < 51) A[m * 112 +  36 + lane] = pose   [r * 51 + lane];
    if (lane <  7) A[m * 112 +  92 + lane] = spatial[r *  7 + lane];
    if (lane < 10) A[m * 112 + 100 + lane] = timex  [r * 10 + lane];
  }

  // ---- proj (relu) + upsample per modality ----
  #pragma unroll
  for (int s = 0; s < 5; ++s) {
    const int hid = HIDs[s];
    if (lane < hid) {
      f32x2 a2[M] = {};
      const f32x4* wp4 = (const f32x4*)(pool + OFF_WPT + WPT_OFF[s]);
      #pragma unroll
      for (int ic = 0; ic < ICNT[s]; ++ic) {
        const f32x4 w = wp4[ic * hid + lane];
        #pragma unroll
        for (int m = 0; m < M; ++m) {
          const f32x4 v = *(const f32x4*)(A + m * 112 + IOFF[s] + ic * 4);
          pkfma(a2[m], v.xy, w.xy);
          pkfma(a2[m], v.zw, w.zw);
        }
      }
      const float bp = BP[s][lane];
      #pragma unroll
      for (int m = 0; m < M; ++m)
        A[448 + m * 160 + HOFF[s] + lane] = fmaxf(a2[m].x + a2[m].y + bp, 0.0f);
    }
    // upsample: all 64 lanes, lane = e
    {
      f32x2 a2[M] = {};
      const f32x4* wu4 = (const f32x4*)(pool + OFF_WUT + WUT_OFF[s]);
      #pragma unroll
      for (int jc = 0; jc < JCNT[s]; ++jc) {
        const f32x4 w = wu4[jc * 64 + lane];
        #pragma unroll
        for (int m = 0; m < M; ++m) {
          const f32x4 h4 = *(const f32x4*)(A + 448 + m * 160 + HOFF[s] + jc * 4);
          pkfma(a2[m], h4.xy, w.xy);
          pkfma(a2[m], h4.zw, w.zw);
        }
      }
      const float bu = BU[s][lane];
      #pragma unroll
      for (int m = 0; m < M; ++m)
        X[m * 320 + s * 64 + lane] = a2[m].x + a2[m].y + bu;
    }
  }

  // ---- fused QKV from hidden (lane = h*16+d) ----
  float qr[M][5], kr[M][5], vr[M][5];
  #pragma unroll
  for (int s = 0; s < 5; ++s) {
    const f32x4* wf = (const f32x4*)(pool + OFF_WFT + WFT_OFF[s]);
    const float* bqp = pool + OFF_BQ + s * 192;
    f32x2 aq[M] = {}, ak[M] = {}, av[M] = {};
    #pragma unroll
    for (int jc = 0; jc < JCNT[s]; ++jc) {
      const f32x4 wq = wf[(0 * JCNT[s] + jc) * 64 + lane];
      const f32x4 wk = wf[(1 * JCNT[s] + jc) * 64 + lane];
      const f32x4 wv = wf[(2 * JCNT[s] + jc) * 64 + lane];
      #pragma unroll
      for (int m = 0; m < M; ++m) {
        const f32x4 h4 = *(const f32x4*)(A + 448 + m * 160 + HOFF[s] + jc * 4);
        pkfma(aq[m], h4.xy, wq.xy); pkfma(aq[m], h4.zw, wq.zw);
        pkfma(ak[m], h4.xy, wk.xy); pkfma(ak[m], h4.zw, wk.zw);
        pkfma(av[m], h4.xy, wv.xy); pkfma(av[m], h4.zw, wv.zw);
      }
    }
    #pragma unroll
    for (int m = 0; m < M; ++m) {
      qr[m][s] = aq[m].x + aq[m].y + bqp[lane];
      kr[m][s] = ak[m].x + ak[m].y + bqp[64 + lane];
      vr[m][s] = av[m].x + av[m].y + bqp[128 + lane];
    }
  }

  // ---- attention in registers (16-lane group reduce over d) ----
  float orr[M][5];
  #pragma unroll
  for (int m = 0; m < M; ++m) {
    #pragma unroll
    for (int qi = 0; qi < 5; ++qi) {
      float sc[5];
      #pragma unroll
      for (int ki = 0; ki < 5; ++ki) {
        float p = qr[m][qi] * kr[m][ki];
        p += __shfl_xor(p, 1); p += __shfl_xor(p, 2);
        p += __shfl_xor(p, 4); p += __shfl_xor(p, 8);
        sc[ki] = p * 0.25f;
      }
      float mx = fmaxf(fmaxf(fmaxf(sc[0], sc[1]), fmaxf(sc[2], sc[3])), sc[4]);
      float ssum = 0.f;
      #pragma unroll
      for (int ki = 0; ki < 5; ++ki) { sc[ki] = __expf(sc[ki] - mx); ssum += sc[ki]; }
      const float inv = 1.0f / ssum;
      float acc = 0.f;
      #pragma unroll
      for (int ki = 0; ki < 5; ++ki) acc += (sc[ki] * inv) * vr[m][ki];
      orr[m][qi] = acc;
    }
  }

  // ---- stage o (overlay region A; in+hid are dead) ----
  #pragma unroll
  for (int m = 0; m < M; ++m)
    #pragma unroll
    for (int s = 0; s < 5; ++s) A[m * 320 + s * 64 + lane] = orr[m][s];

  // ---- output projection (lane = e) ----
  float att[M][5];
  {
    f32x2 a2[M][5] = {};
    const f32x4* wo4 = (const f32x4*)(pool + OFF_WOT);
    #pragma unroll
    for (int hdc = 0; hdc < 16; ++hdc) {
      const f32x4 w = wo4[hdc * 64 + lane];
      #pragma unroll
      for (int m = 0; m < M; ++m)
        #pragma unroll
        for (int s = 0; s < 5; ++s) {
          const f32x4 o4 = *(const f32x4*)(A + m * 320 + s * 64 + hdc * 4);
          pkfma(a2[m][s], o4.xy, w.xy);
          pkfma(a2[m][s], o4.zw, w.zw);
        }
    }
    const float bov = bo[lane];
    #pragma unroll
    for (int m = 0; m < M; ++m)
      #pragma unroll
      for (int s = 0; s < 5; ++s) att[m][s] = a2[m][s].x + a2[m][s].y + bov;
  }

  // ---- residual + LayerNorm -> xg bf16 (pre-swizzled) ----
  {
    const float ga = gamma[lane], be = beta[lane];
    #pragma unroll
    for (int m = 0; m < M; ++m) {
      const int r = rowBase + m;
      char* rowp = xg + (size_t)r * 640;
      const int swz = (r & 7) << 4;
      #pragma unroll
      for (int s = 0; s < 5; ++s) {
        const float hv = X[m * 320 + s * 64 + lane] + att[m][s];
        float s1 = hv, s2 = hv * hv;
        #pragma unroll
        for (int off = 32; off >= 1; off >>= 1) {
          s1 += __shfl_xor(s1, off);
          s2 += __shfl_xor(s2, off);
        }
        const float mean = s1 * 0.015625f;
        const float var  = s2 * 0.015625f - mean * mean;
        const float hn = (hv - mean) * rsqrtf(var + 1e-3f) * ga + be;
        *(short*)(rowp + (((s * 64 + lane) * 2) ^ swz)) = f2bs(hn);
      }
    }
  }
}

// ================= kernel B: MLP via MFMA (proven) =================
__global__ __launch_bounds__(512) void ace_mlp(
    const char* __restrict__ xg,
    const short* __restrict__ W1F, const short* __restrict__ W2F,
    const float* __restrict__ b1, const float* __restrict__ b2,
    float* __restrict__ out)
{
  __shared__ char smem[81920];
  const int tid  = threadIdx.x;
  const int wave = tid >> 6;     // 0..7
  const int lane = tid & 63;
  const int r15 = lane & 15, g4 = lane >> 4;
  const size_t rowBase = (size_t)blockIdx.x * BROWS;

  {
    const char* src = xg + rowBase * 640;
    #pragma unroll
    for (int i = 0; i < 10; ++i) {
      const int off = i * 8192 + wave * 1024;
      GLOAD_LDS16(src + off + lane * 16, smem + off);
    }
  }
  __syncthreads();

  f32x4 acc1[8][2] = {};
  for (int kk = 0; kk < 10; ++kk) {
    short8 b[2];
    #pragma unroll
    for (int nt = 0; nt < 2; ++nt)
      b[nt] = *(const short8*)(W1F + (((wave * 2 + nt) * 10 + kk) * 64 + lane) * 8);
    #pragma unroll
    for (int mt = 0; mt < 8; ++mt) {
      const int row = mt * 16 + r15;
      short8 a = *(const short8*)(smem + row * 640 + ((kk * 64 + g4 * 16) ^ ((row & 7) << 4)));
      #pragma unroll
      for (int nt = 0; nt < 2; ++nt)
        acc1[mt][nt] = __builtin_amdgcn_mfma_f32_16x16x32_bf16(a, b[nt], acc1[mt][nt], 0, 0, 0);
    }
  }
  __syncthreads();

  #pragma unroll
  for (int nt = 0; nt < 2; ++nt) {
    const int c = wave * 32 + nt * 16 + r15;
    const float bias = b1[c];
    #pragma unroll
    for (int mt = 0; mt < 8; ++mt)
      #pragma unroll
      for (int j = 0; j < 4; ++j) {
        const int row = mt * 16 + g4 * 4 + j;
        *(short*)(smem + row * 512 + ((c * 2) ^ ((row & 7) << 4))) =
            f2bs(fmaxf(acc1[mt][nt][j] + bias, 0.0f));
      }
  }
  __syncthreads();

  const int nOwn2 = (wave < 2) ? 2 : 1;
  f32x4 acc2[2][8] = {};
  for (int kk = 0; kk < 8; ++kk) {
    short8 b0 = *(const short8*)(W2F + ((wave * 8 + kk) * 64 + lane) * 8);
    short8 b1f = (wave < 2)
        ? *(const short8*)(W2F + (((8 + wave) * 8 + kk) * 64 + lane) * 8) : short8{};
    #pragma unroll
    for (int mt = 0; mt < 8; ++mt) {
      const int row = mt * 16 + r15;
      short8 a = *(const short8*)(smem + row * 512 + ((kk * 64 + g4 * 16) ^ ((row & 7) << 4)));
      acc2[0][mt] = __builtin_amdgcn_mfma_f32_16x16x32_bf16(a, b0, acc2[0][mt], 0, 0, 0);
      if (wave < 2)
        acc2[1][mt] = __builtin_amdgcn_mfma_f32_16x16x32_bf16(a, b1f, acc2[1][mt], 0, 0, 0);
    }
  }
  __syncthreads();

  #pragma unroll
  for (int t = 0; t < 2; ++t) {
    if (t < nOwn2) {
      const int c = ((t == 0) ? wave : 8 + wave) * 16 + r15;
      const float bias = b2[c];
      #pragma unroll
      for (int mt = 0; mt < 8; ++mt)
        #pragma unroll
        for (int j = 0; j < 4; ++j) {
          const int row = mt * 16 + g4 * 4 + j;
          *(float*)(smem + (row * 160 + c) * 4) = fmaxf(acc2[t][mt][j] + bias, 0.0f);
        }
    }
  }
  __syncthreads();

  {
    f32x4* dst = (f32x4*)(out + rowBase * 160);
    const f32x4* s4 = (const f32x4*)smem;
    #pragma unroll
    for (int i = 0; i < 10; ++i)
      dst[i * 512 + tid] = s4[i * 512 + tid];
  }
}

extern "C" void kernel_launch(void* const* d_in, const int* in_sizes, int n_in,
                              void* d_out, int out_size, void* d_ws, size_t ws_size,
                              hipStream_t stream) {
  const float* visual  = (const float*)d_in[0];
  const float* audio   = (const float*)d_in[1];
  const float* pose    = (const float*)d_in[2];
  const float* spatial = (const float*)d_in[3];
  const float* timex   = (const float*)d_in[4];
  const float* Wv_p = (const float*)d_in[5];  const float* bv_p = (const float*)d_in[6];
  const float* Wa_p = (const float*)d_in[7];  const float* ba_p = (const float*)d_in[8];
  const float* Wp_p = (const float*)d_in[9];  const float* bp_p = (const float*)d_in[10];
  const float* Ws_p = (const float*)d_in[11]; const float* bs_p = (const float*)d_in[12];
  const float* Wt_p = (const float*)d_in[13]; const float* bt_p = (const float*)d_in[14];
  const float* Wv_u = (const float*)d_in[15]; const float* bv_u = (const float*)d_in[16];
  const float* Wa_u = (const float*)d_in[17]; const float* ba_u = (const float*)d_in[18];
  const float* Wp_u = (const float*)d_in[19]; const float* bp_u = (const float*)d_in[20];
  const float* Ws_u = (const float*)d_in[21]; const float* bs_u = (const float*)d_in[22];
  const float* Wt_u = (const float*)d_in[23]; const float* bt_u = (const float*)d_in[24];
  const float* Wq  = (const float*)d_in[25];  const float* bq  = (const float*)d_in[26];
  const float* Wk  = (const float*)d_in[27];  const float* bk  = (const float*)d_in[28];
  const float* Wvv = (const float*)d_in[29];  const float* bvv = (const float*)d_in[30];
  const float* Wo  = (const float*)d_in[31];  const float* bo  = (const float*)d_in[32];
  const float* gamma = (const float*)d_in[33]; const float* beta = (const float*)d_in[34];
  const float* W1 = (const float*)d_in[35];   const float* b1 = (const float*)d_in[36];
  const float* W2 = (const float*)d_in[37];   const float* b2 = (const float*)d_in[38];
  float* out = (float*)d_out;

  short* W1F = (short*)d_ws;                       // bytes [0, 163840)
  short* W2F = W1F + 81920;                        // bytes [163840, 245760)
  float* pool = (float*)((char*)d_ws + 245760);    // bytes [245760, 444928)
  char*  xg  = (char*)d_ws + 524288;               // 80 MiB

  hipLaunchKernelGGL(pack_weights, dim3(480), dim3(256), 0, stream, W1, W2, W1F);
  hipLaunchKernelGGL(pack_front, dim3((POOL_N + 255) / 256), dim3(256), 0, stream,
                     Wv_p, Wa_p, Wp_p, Ws_p, Wt_p,
                     Wv_u, Wa_u, Wp_u, Ws_u, Wt_u,
                     bv_u, ba_u, bp_u, bs_u, bt_u,
                     Wq, Wk, Wvv, bq, bk, bvv, Wo, pool);

  hipLaunchKernelGGL(ace_front, dim3(NROWS / (WAVES * M)), dim3(256), 0, stream,
                     visual, audio, pose, spatial, timex,
                     bv_p, ba_p, bp_p, bs_p, bt_p,
                     bv_u, ba_u, bp_u, bs_u, bt_u,
                     bo, gamma, beta, pool, xg);

  hipLaunchKernelGGL(ace_mlp, dim3(NROWS / BROWS), dim3(512), 0, stream,
                     xg, W1F, W2F, b1, b2, out);
}

// Round 5
// 568.770 us; speedup vs baseline: 3.3952x; 1.0479x over previous
//
#include <hip/hip_runtime.h>
#include <hip/hip_bf16.h>
#include <math.h>

// AttentionContextEncoder, round 5: round-4 front at M=2 rows/wave (occupancy fix).
//  pack_weights: W1,W2 -> bf16 MFMA B-frag tables (proven)
//  pack_front:   fused/transposed fp32 weight tables for the VALU front
//  ace_front:    branches + fused-QKV + attn + Wo + LN, fp32 pk-fma, -> flat bf16 xg
//  ace_mlp:      MFMA MLP (proven)
// B=131072, E=64, H=4, D=16, S=5. Out: (B,160) fp32.

#define NROWS 131072
#define M 2
#define WAVES 4
#define BROWS 128

typedef __attribute__((ext_vector_type(8))) short short8;
typedef __attribute__((ext_vector_type(4))) float f32x4;
typedef __attribute__((ext_vector_type(2))) float f32x2;

__device__ __forceinline__ short f2bs(float f) {
  __hip_bfloat16 h = __float2bfloat16(f);
  return *reinterpret_cast<short*>(&h);
}

__device__ __forceinline__ void pkfma(f32x2& acc, f32x2 a, f32x2 b) {
#if __has_builtin(__builtin_elementwise_fma)
  acc = __builtin_elementwise_fma(a, b, acc);
#else
  acc.x = fmaf(a.x, b.x, acc.x);
  acc.y = fmaf(a.y, b.y, acc.y);
#endif
}

#define GLOAD_LDS16(g, l) __builtin_amdgcn_global_load_lds( \
    (const __attribute__((address_space(1))) void*)(g),     \
    (__attribute__((address_space(3))) void*)(l), 16, 0, 0)

// ---- f32 pool layout (element offsets; pool is 16B-aligned) ----
#define OFF_WPT 0
#define OFF_WUT 3776
#define OFF_WFT 14016
#define OFF_WOT 44736
#define OFF_BQ  48832
#define POOL_N  49792

// ---------------- pack 1: W1,W2 -> bf16 fragment-ordered (proven) ----------------
__global__ void pack_weights(const float* __restrict__ W1, const float* __restrict__ W2,
                             short* __restrict__ ws) {
  int idx = blockIdx.x * blockDim.x + threadIdx.x;
  if (idx < 81920) {
    int i = idx & 7, lane = (idx >> 3) & 63;
    int t = idx >> 9;                 // ntg*10 + kk
    int kk = t % 10, ntg = t / 10;
    int n = ntg * 16 + (lane & 15);
    int k = kk * 32 + (lane >> 4) * 8 + i;
    ws[idx] = f2bs(W1[k * 256 + n]);
  } else if (idx < 81920 + 40960) {
    int j = idx - 81920;
    int i = j & 7, lane = (j >> 3) & 63;
    int t = j >> 9;                   // ntg*8 + kk
    int kk = t & 7, ntg = t >> 3;
    int n = ntg * 16 + (lane & 15);
    int k = kk * 32 + (lane >> 4) * 8 + i;
    ws[81920 + j] = f2bs(W2[k * 160 + n]);
  }
}

// ---------------- pack 2: fused/transposed fp32 front tables ----------------
// WPT[s]: [ICNT][hid][4]   = Wp_s[i][j], zero-padded over i
// WUT[s]: [JCNT][64][4]    = Wu_s[j][e]
// WFT[s]: [3][JCNT][64][4] = sum_e Wu_s[j][e] * W{q,k,v}[e][hd]
// WOT:    [16][64][4]      = Wo[hd][e]
// BQ:     [5][3][64]       = b_{q,k,v}[hd] + sum_e bu_s[e]*W[e][hd]
__global__ void pack_front(
    const float* __restrict__ Wv_p, const float* __restrict__ Wa_p,
    const float* __restrict__ Wp_p, const float* __restrict__ Ws_p,
    const float* __restrict__ Wt_p,
    const float* __restrict__ Wv_u, const float* __restrict__ Wa_u,
    const float* __restrict__ Wp_u, const float* __restrict__ Ws_u,
    const float* __restrict__ Wt_u,
    const float* __restrict__ bv_u, const float* __restrict__ ba_u,
    const float* __restrict__ bp_u, const float* __restrict__ bs_u,
    const float* __restrict__ bt_u,
    const float* __restrict__ Wq, const float* __restrict__ Wk,
    const float* __restrict__ Wvv,
    const float* __restrict__ bq, const float* __restrict__ bk,
    const float* __restrict__ bvv,
    const float* __restrict__ Wo,
    float* __restrict__ pool)
{
  int idx = blockIdx.x * blockDim.x + threadIdx.x;
  if (idx >= POOL_N) return;
  const float* WP[5]  = {Wv_p, Wa_p, Wp_p, Ws_p, Wt_p};
  const float* WU[5]  = {Wv_u, Wa_u, Wp_u, Ws_u, Wt_u};
  const float* BUU[5] = {bv_u, ba_u, bp_u, bs_u, bt_u};
  const float* WT[3]  = {Wq, Wk, Wvv};
  const float* BT[3]  = {bq, bk, bvv};
  const int INs[5]  = {14, 17, 51, 7, 10};
  const int HIDs[5] = {32, 64, 32, 16, 16};
  const int ICNT[5] = {4, 5, 13, 2, 3};
  const int JCNT[5] = {8, 16, 8, 4, 4};
  float val = 0.f;
  if (idx < OFF_WUT) {
    int r = idx, s = 0;
    while (r >= ICNT[s] * HIDs[s] * 4) { r -= ICNT[s] * HIDs[s] * 4; ++s; }
    int ic = r / (HIDs[s] * 4);
    int j  = (r / 4) % HIDs[s];
    int c  = r & 3;
    int i  = ic * 4 + c;
    val = (i < INs[s]) ? WP[s][i * HIDs[s] + j] : 0.f;
  } else if (idx < OFF_WFT) {
    int r = idx - OFF_WUT, s = 0;
    while (r >= JCNT[s] * 256) { r -= JCNT[s] * 256; ++s; }
    int jc = r / 256;
    int e  = (r / 4) & 63;
    int c  = r & 3;
    val = WU[s][(jc * 4 + c) * 64 + e];
  } else if (idx < OFF_WOT) {
    int r = idx - OFF_WFT, s = 0;
    while (r >= 3 * JCNT[s] * 256) { r -= 3 * JCNT[s] * 256; ++s; }
    int t  = r / (JCNT[s] * 256);
    int r2 = r % (JCNT[s] * 256);
    int jc = r2 / 256;
    int hd = (r2 / 4) & 63;
    int c  = r2 & 3;
    int j  = jc * 4 + c;
    float acc = 0.f;
    for (int e = 0; e < 64; ++e) acc += WU[s][j * 64 + e] * WT[t][e * 64 + hd];
    val = acc;
  } else if (idx < OFF_BQ) {
    int r = idx - OFF_WOT;
    int hdc = r / 256;
    int e   = (r / 4) & 63;
    int c   = r & 3;
    val = Wo[(hdc * 4 + c) * 64 + e];
  } else {
    int r = idx - OFF_BQ;
    int s = r / 192;
    int t = (r / 64) % 3;
    int hd = r & 63;
    float acc = BT[t][hd];
    for (int e = 0; e < 64; ++e) acc += BUU[s][e] * WT[t][e * 64 + hd];
    val = acc;
  }
  pool[idx] = val;
}

// ================= kernel A: front, fp32 pk-fma, M=2 rows/wave =================
__global__ __launch_bounds__(256, 4) void ace_front(
    const float* __restrict__ visual, const float* __restrict__ audio,
    const float* __restrict__ pose,   const float* __restrict__ spatial,
    const float* __restrict__ timex,
    const float* __restrict__ bv_p, const float* __restrict__ ba_p,
    const float* __restrict__ bp_p, const float* __restrict__ bs_p,
    const float* __restrict__ bt_p,
    const float* __restrict__ bv_u, const float* __restrict__ ba_u,
    const float* __restrict__ bp_u, const float* __restrict__ bs_u,
    const float* __restrict__ bt_u,
    const float* __restrict__ bo, const float* __restrict__ gamma,
    const float* __restrict__ beta,
    const float* __restrict__ pool,
    char* __restrict__ xg)   // bf16 [NROWS][320], byte (col*2)^((row&7)<<4)
{
  // per-wave LDS (1280 floats):
  //   region A [0..640): in[m][112] @0 (224) + hid[m][160] @224 (320);
  //   o[m][320] overlays A [0..640) after QKV;  X [640..1280): x[m][s][64]
  __shared__ float lds[WAVES][1280];
  const int tid  = threadIdx.x;
  const int wave = tid >> 6;
  const int lane = tid & 63;
  float* A = lds[wave];
  float* X = A + 640;
  const int rowBase = (blockIdx.x * WAVES + wave) * M;

  const int HIDs[5] = {32, 64, 32, 16, 16};
  const int ICNT[5] = {4, 5, 13, 2, 3};
  const int JCNT[5] = {8, 16, 8, 4, 4};
  const int IOFF[5] = {0, 16, 36, 92, 100};
  const int HOFF[5] = {0, 32, 96, 128, 144};
  const int WPT_OFF[5] = {0, 512, 1792, 3456, 3584};
  const int WUT_OFF[5] = {0, 2048, 6144, 8192, 9216};
  const int WFT_OFF[5] = {0, 6144, 18432, 24576, 27648};
  const float* BP[5] = {bv_p, ba_p, bp_p, bs_p, bt_p};
  const float* BU[5] = {bv_u, ba_u, bp_u, bs_u, bt_u};

  // ---- zero padded input region [0..224), then stage raw inputs ----
  #pragma unroll
  for (int k2 = 0; k2 < 4; ++k2) {
    const int idx = k2 * 64 + lane;
    if (idx < 224) A[idx] = 0.f;
  }
  #pragma unroll
  for (int m = 0; m < M; ++m) {
    const int r = rowBase + m;
    if (lane < 14) A[m * 112 +   0 + lane] = visual [r * 14 + lane];
    if (lane < 17) A[m * 112 +  16 + lane] = audio  [r * 17 + lane];
    if (lane < 51) A[m * 112 +  36 + lane] = pose   [r * 51 + lane];
    if (lane <  7) A[m * 112 +  92 + lane] = spatial[r *  7 + lane];
    if (lane < 10) A[m * 112 + 100 + lane] = timex  [r * 10 + lane];
  }

  // ---- proj (relu) + upsample per modality ----
  #pragma unroll
  for (int s = 0; s < 5; ++s) {
    const int hid = HIDs[s];
    if (lane < hid) {
      f32x2 a2[M] = {};
      const f32x4* wp4 = (const f32x4*)(pool + OFF_WPT + WPT_OFF[s]);
      #pragma unroll
      for (int ic = 0; ic < ICNT[s]; ++ic) {
        const f32x4 w = wp4[ic * hid + lane];
        #pragma unroll
        for (int m = 0; m < M; ++m) {
          const f32x4 v = *(const f32x4*)(A + m * 112 + IOFF[s] + ic * 4);
          pkfma(a2[m], v.xy, w.xy);
          pkfma(a2[m], v.zw, w.zw);
        }
      }
      const float bp = BP[s][lane];
      #pragma unroll
      for (int m = 0; m < M; ++m)
        A[224 + m * 160 + HOFF[s] + lane] = fmaxf(a2[m].x + a2[m].y + bp, 0.0f);
    }
    // upsample: all 64 lanes, lane = e
    {
      f32x2 a2[M] = {};
      const f32x4* wu4 = (const f32x4*)(pool + OFF_WUT + WUT_OFF[s]);
      #pragma unroll
      for (int jc = 0; jc < JCNT[s]; ++jc) {
        const f32x4 w = wu4[jc * 64 + lane];
        #pragma unroll
        for (int m = 0; m < M; ++m) {
          const f32x4 h4 = *(const f32x4*)(A + 224 + m * 160 + HOFF[s] + jc * 4);
          pkfma(a2[m], h4.xy, w.xy);
          pkfma(a2[m], h4.zw, w.zw);
        }
      }
      const float bu = BU[s][lane];
      #pragma unroll
      for (int m = 0; m < M; ++m)
        X[m * 320 + s * 64 + lane] = a2[m].x + a2[m].y + bu;
    }
  }

  // ---- fused QKV from hidden (lane = h*16+d) ----
  float qr[M][5], kr[M][5], vr[M][5];
  #pragma unroll
  for (int s = 0; s < 5; ++s) {
    const f32x4* wf = (const f32x4*)(pool + OFF_WFT + WFT_OFF[s]);
    const float* bqp = pool + OFF_BQ + s * 192;
    f32x2 aq[M] = {}, ak[M] = {}, av[M] = {};
    #pragma unroll
    for (int jc = 0; jc < JCNT[s]; ++jc) {
      const f32x4 wq = wf[(0 * JCNT[s] + jc) * 64 + lane];
      const f32x4 wk = wf[(1 * JCNT[s] + jc) * 64 + lane];
      const f32x4 wv = wf[(2 * JCNT[s] + jc) * 64 + lane];
      #pragma unroll
      for (int m = 0; m < M; ++m) {
        const f32x4 h4 = *(const f32x4*)(A + 224 + m * 160 + HOFF[s] + jc * 4);
        pkfma(aq[m], h4.xy, wq.xy); pkfma(aq[m], h4.zw, wq.zw);
        pkfma(ak[m], h4.xy, wk.xy); pkfma(ak[m], h4.zw, wk.zw);
        pkfma(av[m], h4.xy, wv.xy); pkfma(av[m], h4.zw, wv.zw);
      }
    }
    #pragma unroll
    for (int m = 0; m < M; ++m) {
      qr[m][s] = aq[m].x + aq[m].y + bqp[lane];
      kr[m][s] = ak[m].x + ak[m].y + bqp[64 + lane];
      vr[m][s] = av[m].x + av[m].y + bqp[128 + lane];
    }
  }

  // ---- attention in registers (16-lane group reduce over d) ----
  float orr[M][5];
  #pragma unroll
  for (int m = 0; m < M; ++m) {
    #pragma unroll
    for (int qi = 0; qi < 5; ++qi) {
      float sc[5];
      #pragma unroll
      for (int ki = 0; ki < 5; ++ki) {
        float p = qr[m][qi] * kr[m][ki];
        p += __shfl_xor(p, 1); p += __shfl_xor(p, 2);
        p += __shfl_xor(p, 4); p += __shfl_xor(p, 8);
        sc[ki] = p * 0.25f;
      }
      float mx = fmaxf(fmaxf(fmaxf(sc[0], sc[1]), fmaxf(sc[2], sc[3])), sc[4]);
      float ssum = 0.f;
      #pragma unroll
      for (int ki = 0; ki < 5; ++ki) { sc[ki] = __expf(sc[ki] - mx); ssum += sc[ki]; }
      const float inv = 1.0f / ssum;
      float acc = 0.f;
      #pragma unroll
      for (int ki = 0; ki < 5; ++ki) acc += (sc[ki] * inv) * vr[m][ki];
      orr[m][qi] = acc;
    }
  }

  // ---- stage o (overlay region A; in+hid are dead) ----
  #pragma unroll
  for (int m = 0; m < M; ++m)
    #pragma unroll
    for (int s = 0; s < 5; ++s) A[m * 320 + s * 64 + lane] = orr[m][s];

  // ---- output projection (lane = e) ----
  float att[M][5];
  {
    f32x2 a2[M][5] = {};
    const f32x4* wo4 = (const f32x4*)(pool + OFF_WOT);
    #pragma unroll
    for (int hdc = 0; hdc < 16; ++hdc) {
      const f32x4 w = wo4[hdc * 64 + lane];
      #pragma unroll
      for (int m = 0; m < M; ++m)
        #pragma unroll
        for (int s = 0; s < 5; ++s) {
          const f32x4 o4 = *(const f32x4*)(A + m * 320 + s * 64 + hdc * 4);
          pkfma(a2[m][s], o4.xy, w.xy);
          pkfma(a2[m][s], o4.zw, w.zw);
        }
    }
    const float bov = bo[lane];
    #pragma unroll
    for (int m = 0; m < M; ++m)
      #pragma unroll
      for (int s = 0; s < 5; ++s) att[m][s] = a2[m][s].x + a2[m][s].y + bov;
  }

  // ---- residual + LayerNorm -> xg bf16 (pre-swizzled) ----
  {
    const float ga = gamma[lane], be = beta[lane];
    #pragma unroll
    for (int m = 0; m < M; ++m) {
      const int r = rowBase + m;
      char* rowp = xg + (size_t)r * 640;
      const int swz = (r & 7) << 4;
      #pragma unroll
      for (int s = 0; s < 5; ++s) {
        const float hv = X[m * 320 + s * 64 + lane] + att[m][s];
        float s1 = hv, s2 = hv * hv;
        #pragma unroll
        for (int off = 32; off >= 1; off >>= 1) {
          s1 += __shfl_xor(s1, off);
          s2 += __shfl_xor(s2, off);
        }
        const float mean = s1 * 0.015625f;
        const float var  = s2 * 0.015625f - mean * mean;
        const float hn = (hv - mean) * rsqrtf(var + 1e-3f) * ga + be;
        *(short*)(rowp + (((s * 64 + lane) * 2) ^ swz)) = f2bs(hn);
      }
    }
  }
}

// ================= kernel B: MLP via MFMA (proven) =================
__global__ __launch_bounds__(512) void ace_mlp(
    const char* __restrict__ xg,
    const short* __restrict__ W1F, const short* __restrict__ W2F,
    const float* __restrict__ b1, const float* __restrict__ b2,
    float* __restrict__ out)
{
  __shared__ char smem[81920];
  const int tid  = threadIdx.x;
  const int wave = tid >> 6;     // 0..7
  const int lane = tid & 63;
  const int r15 = lane & 15, g4 = lane >> 4;
  const size_t rowBase = (size_t)blockIdx.x * BROWS;

  {
    const char* src = xg + rowBase * 640;
    #pragma unroll
    for (int i = 0; i < 10; ++i) {
      const int off = i * 8192 + wave * 1024;
      GLOAD_LDS16(src + off + lane * 16, smem + off);
    }
  }
  __syncthreads();

  f32x4 acc1[8][2] = {};
  for (int kk = 0; kk < 10; ++kk) {
    short8 b[2];
    #pragma unroll
    for (int nt = 0; nt < 2; ++nt)
      b[nt] = *(const short8*)(W1F + (((wave * 2 + nt) * 10 + kk) * 64 + lane) * 8);
    #pragma unroll
    for (int mt = 0; mt < 8; ++mt) {
      const int row = mt * 16 + r15;
      short8 a = *(const short8*)(smem + row * 640 + ((kk * 64 + g4 * 16) ^ ((row & 7) << 4)));
      #pragma unroll
      for (int nt = 0; nt < 2; ++nt)
        acc1[mt][nt] = __builtin_amdgcn_mfma_f32_16x16x32_bf16(a, b[nt], acc1[mt][nt], 0, 0, 0);
    }
  }
  __syncthreads();

  #pragma unroll
  for (int nt = 0; nt < 2; ++nt) {
    const int c = wave * 32 + nt * 16 + r15;
    const float bias = b1[c];
    #pragma unroll
    for (int mt = 0; mt < 8; ++mt)
      #pragma unroll
      for (int j = 0; j < 4; ++j) {
        const int row = mt * 16 + g4 * 4 + j;
        *(short*)(smem + row * 512 + ((c * 2) ^ ((row & 7) << 4))) =
            f2bs(fmaxf(acc1[mt][nt][j] + bias, 0.0f));
      }
  }
  __syncthreads();

  const int nOwn2 = (wave < 2) ? 2 : 1;
  f32x4 acc2[2][8] = {};
  for (int kk = 0; kk < 8; ++kk) {
    short8 b0 = *(const short8*)(W2F + ((wave * 8 + kk) * 64 + lane) * 8);
    short8 b1f = (wave < 2)
        ? *(const short8*)(W2F + (((8 + wave) * 8 + kk) * 64 + lane) * 8) : short8{};
    #pragma unroll
    for (int mt = 0; mt < 8; ++mt) {
      const int row = mt * 16 + r15;
      short8 a = *(const short8*)(smem + row * 512 + ((kk * 64 + g4 * 16) ^ ((row & 7) << 4)));
      acc2[0][mt] = __builtin_amdgcn_mfma_f32_16x16x32_bf16(a, b0, acc2[0][mt], 0, 0, 0);
      if (wave < 2)
        acc2[1][mt] = __builtin_amdgcn_mfma_f32_16x16x32_bf16(a, b1f, acc2[1][mt], 0, 0, 0);
    }
  }
  __syncthreads();

  #pragma unroll
  for (int t = 0; t < 2; ++t) {
    if (t < nOwn2) {
      const int c = ((t == 0) ? wave : 8 + wave) * 16 + r15;
      const float bias = b2[c];
      #pragma unroll
      for (int mt = 0; mt < 8; ++mt)
        #pragma unroll
        for (int j = 0; j < 4; ++j) {
          const int row = mt * 16 + g4 * 4 + j;
          *(float*)(smem + (row * 160 + c) * 4) = fmaxf(acc2[t][mt][j] + bias, 0.0f);
        }
    }
  }
  __syncthreads();

  {
    f32x4* dst = (f32x4*)(out + rowBase * 160);
    const f32x4* s4 = (const f32x4*)smem;
    #pragma unroll
    for (int i = 0; i < 10; ++i)
      dst[i * 512 + tid] = s4[i * 512 + tid];
  }
}

extern "C" void kernel_launch(void* const* d_in, const int* in_sizes, int n_in,
                              void* d_out, int out_size, void* d_ws, size_t ws_size,
                              hipStream_t stream) {
  const float* visual  = (const float*)d_in[0];
  const float* audio   = (const float*)d_in[1];
  const float* pose    = (const float*)d_in[2];
  const float* spatial = (const float*)d_in[3];
  const float* timex   = (const float*)d_in[4];
  const float* Wv_p = (const float*)d_in[5];  const float* bv_p = (const float*)d_in[6];
  const float* Wa_p = (const float*)d_in[7];  const float* ba_p = (const float*)d_in[8];
  const float* Wp_p = (const float*)d_in[9];  const float* bp_p = (const float*)d_in[10];
  const float* Ws_p = (const float*)d_in[11]; const float* bs_p = (const float*)d_in[12];
  const float* Wt_p = (const float*)d_in[13]; const float* bt_p = (const float*)d_in[14];
  const float* Wv_u = (const float*)d_in[15]; const float* bv_u = (const float*)d_in[16];
  const float* Wa_u = (const float*)d_in[17]; const float* ba_u = (const float*)d_in[18];
  const float* Wp_u = (const float*)d_in[19]; const float* bp_u = (const float*)d_in[20];
  const float* Ws_u = (const float*)d_in[21]; const float* bs_u = (const float*)d_in[22];
  const float* Wt_u = (const float*)d_in[23]; const float* bt_u = (const float*)d_in[24];
  const float* Wq  = (const float*)d_in[25];  const float* bq  = (const float*)d_in[26];
  const float* Wk  = (const float*)d_in[27];  const float* bk  = (const float*)d_in[28];
  const float* Wvv = (const float*)d_in[29];  const float* bvv = (const float*)d_in[30];
  const float* Wo  = (const float*)d_in[31];  const float* bo  = (const float*)d_in[32];
  const float* gamma = (const float*)d_in[33]; const float* beta = (const float*)d_in[34];
  const float* W1 = (const float*)d_in[35];   const float* b1 = (const float*)d_in[36];
  const float* W2 = (const float*)d_in[37];   const float* b2 = (const float*)d_in[38];
  float* out = (float*)d_out;

  short* W1F = (short*)d_ws;                       // bytes [0, 163840)
  short* W2F = W1F + 81920;                        // bytes [163840, 245760)
  float* pool = (float*)((char*)d_ws + 245760);    // bytes [245760, 444928)
  char*  xg  = (char*)d_ws + 524288;               // 80 MiB

  hipLaunchKernelGGL(pack_weights, dim3(480), dim3(256), 0, stream, W1, W2, W1F);
  hipLaunchKernelGGL(pack_front, dim3((POOL_N + 255) / 256), dim3(256), 0, stream,
                     Wv_p, Wa_p, Wp_p, Ws_p, Wt_p,
                     Wv_u, Wa_u, Wp_u, Ws_u, Wt_u,
                     bv_u, ba_u, bp_u, bs_u, bt_u,
                     Wq, Wk, Wvv, bq, bk, bvv, Wo, pool);

  hipLaunchKernelGGL(ace_front, dim3(NROWS / (WAVES * M)), dim3(256), 0, stream,
                     visual, audio, pose, spatial, timex,
                     bv_p, ba_p, bp_p, bs_p, bt_p,
                     bv_u, ba_u, bp_u, bs_u, bt_u,
                     bo, gamma, beta, pool, xg);

  hipLaunchKernelGGL(ace_mlp, dim3(NROWS / BROWS), dim3(512), 0, stream,
                     xg, W1F, W2F, b1, b2, out);
}